// Round 2
// baseline (1153.394 us; speedup 1.0000x reference)
//
#include <hip/hip_runtime.h>

#define EPS_DENOM 1e-7f
#define EPS_NORM  1e-5f

static constexpr int D = 32;   // feature dim
static constexpr int H = 128;  // hidden dim

// ---------------------------------------------------------------------------
// FCNN: out = relu(x@W1+b1)@W2+b2 for one parameter set.
// One thread per node. Small loop body (~64 FMA) to stay in I-cache.
// Weights are wave-uniform -> scalar loads.
// ---------------------------------------------------------------------------
__global__ __launch_bounds__(256) void fcnn_kernel(
    const float* __restrict__ x,
    const float* __restrict__ W1, const float* __restrict__ b1,
    const float* __restrict__ W2, const float* __restrict__ b2,
    float* __restrict__ out, int N)
{
    int n = blockIdx.x * blockDim.x + threadIdx.x;
    if (n >= N) return;

    float xr[D];
    const float4* xv = (const float4*)(x + (size_t)n * D);
    #pragma unroll
    for (int i = 0; i < D / 4; ++i) {
        float4 v = xv[i];
        xr[4*i+0] = v.x; xr[4*i+1] = v.y; xr[4*i+2] = v.z; xr[4*i+3] = v.w;
    }

    float acc[D];
    #pragma unroll
    for (int d = 0; d < D; ++d) acc[d] = b2[d];

    for (int h = 0; h < H; ++h) {   // no outer unroll: keep body ~0.6 KB
        float t = b1[h];
        #pragma unroll
        for (int i = 0; i < D; ++i) t = fmaf(xr[i], W1[i * H + h], t);
        t = fmaxf(t, 0.0f);
        #pragma unroll
        for (int d = 0; d < D; ++d) acc[d] = fmaf(t, W2[h * D + d], acc[d]);
    }

    float4* o = (float4*)(out + (size_t)n * D);
    #pragma unroll
    for (int i = 0; i < D / 4; ++i)
        o[i] = make_float4(acc[4*i], acc[4*i+1], acc[4*i+2], acc[4*i+3]);
}

// ---------------------------------------------------------------------------
// CSR build step 1: degree count (both directions). int atomics only.
// ---------------------------------------------------------------------------
__global__ __launch_bounds__(256) void count_kernel(
    const int* __restrict__ ei, int* __restrict__ deg, int E)
{
    int e = blockIdx.x * blockDim.x + threadIdx.x;
    if (e >= E) return;
    atomicAdd(&deg[ei[e]], 1);
    atomicAdd(&deg[ei[E + e]], 1);
}

// ---------------------------------------------------------------------------
// CSR build step 2: two-level exclusive scan of deg -> cursor.
// ---------------------------------------------------------------------------
__global__ __launch_bounds__(256) void scan1_kernel(
    const int* __restrict__ deg, int* __restrict__ cursor,
    int* __restrict__ bsum, int N)
{
    __shared__ int tmp[256];
    int tid = threadIdx.x;
    int i = blockIdx.x * 256 + tid;
    int v = (i < N) ? deg[i] : 0;
    tmp[tid] = v;
    __syncthreads();
    #pragma unroll
    for (int off = 1; off < 256; off <<= 1) {
        int t = (tid >= off) ? tmp[tid - off] : 0;
        __syncthreads();
        tmp[tid] += t;
        __syncthreads();
    }
    if (i < N) cursor[i] = tmp[tid] - v;          // exclusive
    if (tid == 255) bsum[blockIdx.x] = tmp[255];  // block total
}

__global__ __launch_bounds__(512) void scan2_kernel(int* __restrict__ bsum, int nb)
{
    __shared__ int tmp[512];
    int tid = threadIdx.x;
    int v = (tid < nb) ? bsum[tid] : 0;
    tmp[tid] = v;
    __syncthreads();
    #pragma unroll
    for (int off = 1; off < 512; off <<= 1) {
        int t = (tid >= off) ? tmp[tid - off] : 0;
        __syncthreads();
        tmp[tid] += t;
        __syncthreads();
    }
    if (tid < nb) bsum[tid] = tmp[tid] - v;       // exclusive
}

__global__ __launch_bounds__(256) void scan3_kernel(
    int* __restrict__ cursor, const int* __restrict__ bsum, int N)
{
    int i = blockIdx.x * 256 + threadIdx.x;
    if (i < N) cursor[i] += bsum[blockIdx.x];
}

// ---------------------------------------------------------------------------
// CSR build step 3: fill adjacency (edge ids only).
// After this, cursor[n] == rowptr[n+1].
// ---------------------------------------------------------------------------
__global__ __launch_bounds__(256) void fill_kernel(
    const int* __restrict__ ei, int* __restrict__ cursor,
    int* __restrict__ adj, int E)
{
    int e = blockIdx.x * blockDim.x + threadIdx.x;
    if (e >= E) return;
    int a = ei[e];
    int b = ei[E + e];
    int pa = atomicAdd(&cursor[a], 1);
    adj[pa] = e;
    int pb = atomicAdd(&cursor[b], 1);
    adj[pb] = e;
}

// ---------------------------------------------------------------------------
// Gather + finalize. 32 lanes per node (lane = feature d).
//   s_sum[d]  = sum over incident edges of sigmoid(ef[e][d])
//   sh_sum[d] = sum of sigmoid(ef[e][d]) * h2[nbr][d]
//   h = h1 + sh_sum/(eps + s_sum); InstanceNorm over d; out = x + relu(hn)
// ---------------------------------------------------------------------------
__global__ __launch_bounds__(256) void gather_kernel(
    const float* __restrict__ x,  const float* __restrict__ ef,
    const int*   __restrict__ ei, const float* __restrict__ h1,
    const float* __restrict__ h2, const int* __restrict__ deg,
    const int*   __restrict__ cursor, const int* __restrict__ adj,
    float* __restrict__ out, int N, int E)
{
    int t = blockIdx.x * blockDim.x + threadIdx.x;
    int n = t >> 5;
    int d = t & 31;
    if (n >= N) return;

    int dg    = deg[n];
    int end   = cursor[n];       // rowptr[n+1] after fill
    int start = end - dg;

    float s_sum = 0.0f, sh_sum = 0.0f;
    for (int k = start; k < end; ++k) {
        int e = adj[k];                       // broadcast across 32 lanes
        int a = ei[e];
        int b = ei[E + e];
        int nbr = (a == n) ? b : a;
        float v = ef[(size_t)e * D + d];      // coalesced 128B row
        float s = 1.0f / (1.0f + __expf(-v));
        float hh = h2[(size_t)nbr * D + d];   // coalesced 128B row
        s_sum += s;
        sh_sum = fmaf(s, hh, sh_sum);
    }

    size_t idx = (size_t)n * D + d;
    float h = h1[idx] + sh_sum / (EPS_DENOM + s_sum);

    float sum = h, sq = h * h;
    #pragma unroll
    for (int off = 16; off > 0; off >>= 1) {
        sum += __shfl_xor(sum, off, 32);
        sq  += __shfl_xor(sq,  off, 32);
    }
    float mu  = sum * (1.0f / 32.0f);
    float var = fmaxf(sq * (1.0f / 32.0f) - mu * mu, 0.0f);
    float hn  = (h - mu) * rsqrtf(var + EPS_NORM);

    out[idx] = x[idx] + fmaxf(hn, 0.0f);
}

// ---------------------------------------------------------------------------
extern "C" void kernel_launch(void* const* d_in, const int* in_sizes, int n_in,
                              void* d_out, int out_size, void* d_ws, size_t ws_size,
                              hipStream_t stream)
{
    const float* x   = (const float*)d_in[0];
    const float* ef  = (const float*)d_in[1];
    const float* W1a = (const float*)d_in[2];
    const float* b1a = (const float*)d_in[3];
    const float* W2a = (const float*)d_in[4];
    const float* b2a = (const float*)d_in[5];
    const float* W1b = (const float*)d_in[6];
    const float* b1b = (const float*)d_in[7];
    const float* W2b = (const float*)d_in[8];
    const float* b2b = (const float*)d_in[9];
    const int*   ei  = (const int*)d_in[10];
    float* out = (float*)d_out;

    const int N = in_sizes[0] / D;
    const int E = in_sizes[1] / D;
    const int nb = (N + 255) / 256;   // scan blocks (391 for N=100k, <=512)

    // workspace layout
    float* h1     = (float*)d_ws;
    float* h2     = h1 + (size_t)N * D;
    int*   deg    = (int*)(h2 + (size_t)N * D);
    int*   cursor = deg + N;
    int*   bsum   = cursor + N;
    int*   adj    = bsum + 512;       // 2E ints

    hipMemsetAsync(deg, 0, (size_t)N * sizeof(int), stream);

    fcnn_kernel<<<(N + 255) / 256, 256, 0, stream>>>(x, W1a, b1a, W2a, b2a, h1, N);
    fcnn_kernel<<<(N + 255) / 256, 256, 0, stream>>>(x, W1b, b1b, W2b, b2b, h2, N);

    count_kernel<<<(E + 255) / 256, 256, 0, stream>>>(ei, deg, E);
    scan1_kernel<<<nb, 256, 0, stream>>>(deg, cursor, bsum, N);
    scan2_kernel<<<1, 512, 0, stream>>>(bsum, nb);
    scan3_kernel<<<nb, 256, 0, stream>>>(cursor, bsum, N);
    fill_kernel<<<(E + 255) / 256, 256, 0, stream>>>(ei, cursor, adj, E);

    gather_kernel<<<((size_t)N * 32 + 255) / 256, 256, 0, stream>>>(
        x, ef, ei, h1, h2, deg, cursor, adj, out, N, E);
}

// Round 3
// 961.046 us; speedup vs baseline: 1.2001x; 1.2001x over previous
//
#include <hip/hip_runtime.h>

#define EPS_DENOM 1e-7f
#define EPS_NORM  1e-5f

static constexpr int D = 32;   // feature dim
static constexpr int H = 128;  // hidden dim

typedef _Float16 f16x8 __attribute__((ext_vector_type(8)));
typedef float    f32x4 __attribute__((ext_vector_type(4)));

// ---------------------------------------------------------------------------
// FCNN via fp16 MFMA. Block = 256 threads = 4 waves = 64 nodes (16/wave).
// LDS (halfwords):
//   xk   [64][40]    @ 0       (x tile, fp16, row-padded 32->40)
//   w1t  [128][40]x2 @ 2560    (W1^T per FCNN: [h][k])
//   w2t  [32][136]x2 @ 12800   (W2^T per FCNN: [d][k], 128->136)
//   t1   [4][16][136]@ 21504   (per-wave relu(layer1) in A-layout)
// Total 30208 hw = 60416 B.
// Layer1: C[16n x 16h] = A(x) * B(W1), K=32, one MFMA per h-tile (8).
// Layer2: C[16n x 16d] = A(t1) * B(W2), K=128, 4 MFMA per d-tile (2).
// MFMA A: lane holds A[m=lane&15][k=(lane>>4)*8+j]; B: B[k=(lane>>4)*8+j][n=lane&15];
// C/D: lane,reg r -> C[(lane>>4)*4+r][lane&15].
// ---------------------------------------------------------------------------
__global__ __launch_bounds__(256) void fcnn_mfma_kernel(
    const float* __restrict__ x,
    const float* __restrict__ W1a, const float* __restrict__ b1a,
    const float* __restrict__ W2a, const float* __restrict__ b2a,
    const float* __restrict__ W1b, const float* __restrict__ b1b,
    const float* __restrict__ W2b, const float* __restrict__ b2b,
    float* __restrict__ h1, _Float16* __restrict__ h2h, int N)
{
    __shared__ _Float16 lds[30208];
    _Float16* xk = lds;

    const int tid = threadIdx.x;
    const int nb0 = blockIdx.x * 64;

    // ---- stage x tile (zero-pad OOB nodes) ----
    #pragma unroll
    for (int t = 0; t < 8; ++t) {
        int f = t * 256 + tid;
        int node = f >> 5, off = f & 31;
        int gn = nb0 + node;
        float v = (gn < N) ? x[(size_t)gn * 32 + off] : 0.0f;
        xk[node * 40 + off] = (_Float16)v;
    }
    // ---- stage weights (fp32 -> fp16, transposed) ----
    for (int fc = 0; fc < 2; ++fc) {
        const float* W1 = fc ? W1b : W1a;
        const float* W2 = fc ? W2b : W2a;
        _Float16* w1t = lds + 2560 + fc * 5120;    // [h][k], stride 40
        _Float16* w2t = lds + 12800 + fc * 4352;   // [d][k], stride 136
        #pragma unroll
        for (int t = 0; t < 16; ++t) {
            int f = t * 256 + tid;                 // W1 flat [k][h]
            w1t[(f & 127) * 40 + (f >> 7)] = (_Float16)W1[f];
        }
        #pragma unroll
        for (int t = 0; t < 16; ++t) {
            int f = t * 256 + tid;                 // W2 flat [k][d]
            w2t[(f & 31) * 136 + (f >> 5)] = (_Float16)W2[f];
        }
    }
    __syncthreads();

    const int wid  = tid >> 6;
    const int lane = tid & 63;
    const int m    = lane & 15;
    const int g    = lane >> 4;
    _Float16* t1 = lds + 21504 + wid * 2176;

    f16x8 ax = *(const f16x8*)(xk + (wid * 16 + m) * 40 + g * 8);

    for (int fc = 0; fc < 2; ++fc) {
        const float* b1v = fc ? b1b : b1a;
        const float* b2v = fc ? b2b : b2a;
        const _Float16* w1t = lds + 2560 + fc * 5120;
        const _Float16* w2t = lds + 12800 + fc * 4352;

        // layer 1: 8 h-tiles, K=32 (single MFMA each)
        for (int hb = 0; hb < 8; ++hb) {
            f16x8 bw = *(const f16x8*)(w1t + (hb * 16 + m) * 40 + g * 8);
            f32x4 c = {0.f, 0.f, 0.f, 0.f};
            c = __builtin_amdgcn_mfma_f32_16x16x32_f16(ax, bw, c, 0, 0, 0);
            float bias = b1v[hb * 16 + m];
            #pragma unroll
            for (int r = 0; r < 4; ++r) {
                float tv = fmaxf(c[r] + bias, 0.0f);
                t1[(g * 4 + r) * 136 + hb * 16 + m] = (_Float16)tv;
            }
        }

        // layer 2: 2 d-tiles, K=128 (4 MFMA each)
        for (int dt = 0; dt < 2; ++dt) {
            f32x4 c2 = {0.f, 0.f, 0.f, 0.f};
            #pragma unroll
            for (int kc = 0; kc < 4; ++kc) {
                f16x8 a2  = *(const f16x8*)(t1 + m * 136 + kc * 32 + g * 8);
                f16x8 b2w = *(const f16x8*)(w2t + (dt * 16 + m) * 136 + kc * 32 + g * 8);
                c2 = __builtin_amdgcn_mfma_f32_16x16x32_f16(a2, b2w, c2, 0, 0, 0);
            }
            float bias = b2v[dt * 16 + m];
            #pragma unroll
            for (int r = 0; r < 4; ++r) {
                int gn = nb0 + wid * 16 + g * 4 + r;
                if (gn < N) {
                    float val = c2[r] + bias;
                    if (fc == 0) h1[(size_t)gn * 32 + dt * 16 + m] = val;
                    else         h2h[(size_t)gn * 32 + dt * 16 + m] = (_Float16)val;
                }
            }
        }
        __syncthreads();   // t1 reused by next fc phase
    }
}

// ---------------------------------------------------------------------------
// sigmoid(ef) -> fp16, edge order (coalesced). 4 elements per thread.
// ---------------------------------------------------------------------------
__global__ __launch_bounds__(256) void sprep_kernel(
    const float* __restrict__ ef, _Float16* __restrict__ sgh, int n4)
{
    int i = blockIdx.x * blockDim.x + threadIdx.x;
    if (i >= n4) return;
    float4 v = ((const float4*)ef)[i];
    _Float16 r[4];
    r[0] = (_Float16)(1.0f / (1.0f + __expf(-v.x)));
    r[1] = (_Float16)(1.0f / (1.0f + __expf(-v.y)));
    r[2] = (_Float16)(1.0f / (1.0f + __expf(-v.z)));
    r[3] = (_Float16)(1.0f / (1.0f + __expf(-v.w)));
    ((uint2*)sgh)[i] = *(const uint2*)r;
}

// ---------------------------------------------------------------------------
// CSR build: count -> scan(3) -> fill (adj packs {nbr, edge})
// ---------------------------------------------------------------------------
__global__ __launch_bounds__(256) void count_kernel(
    const int* __restrict__ ei, int* __restrict__ deg, int E)
{
    int e = blockIdx.x * blockDim.x + threadIdx.x;
    if (e >= E) return;
    atomicAdd(&deg[ei[e]], 1);
    atomicAdd(&deg[ei[E + e]], 1);
}

__global__ __launch_bounds__(256) void scan1_kernel(
    const int* __restrict__ deg, int* __restrict__ cursor,
    int* __restrict__ bsum, int N)
{
    __shared__ int tmp[256];
    int tid = threadIdx.x;
    int i = blockIdx.x * 256 + tid;
    int v = (i < N) ? deg[i] : 0;
    tmp[tid] = v;
    __syncthreads();
    #pragma unroll
    for (int off = 1; off < 256; off <<= 1) {
        int t = (tid >= off) ? tmp[tid - off] : 0;
        __syncthreads();
        tmp[tid] += t;
        __syncthreads();
    }
    if (i < N) cursor[i] = tmp[tid] - v;
    if (tid == 255) bsum[blockIdx.x] = tmp[255];
}

__global__ __launch_bounds__(512) void scan2_kernel(int* __restrict__ bsum, int nb)
{
    __shared__ int tmp[512];
    int tid = threadIdx.x;
    int v = (tid < nb) ? bsum[tid] : 0;
    tmp[tid] = v;
    __syncthreads();
    #pragma unroll
    for (int off = 1; off < 512; off <<= 1) {
        int t = (tid >= off) ? tmp[tid - off] : 0;
        __syncthreads();
        tmp[tid] += t;
        __syncthreads();
    }
    if (tid < nb) bsum[tid] = tmp[tid] - v;
}

__global__ __launch_bounds__(256) void scan3_kernel(
    int* __restrict__ cursor, const int* __restrict__ bsum, int N)
{
    int i = blockIdx.x * 256 + threadIdx.x;
    if (i < N) cursor[i] += bsum[blockIdx.x];
}

__global__ __launch_bounds__(256) void fill_kernel(
    const int* __restrict__ ei, int* __restrict__ cursor,
    int2* __restrict__ adj, int E)
{
    int e = blockIdx.x * blockDim.x + threadIdx.x;
    if (e >= E) return;
    int a = ei[e];
    int b = ei[E + e];
    int pa = atomicAdd(&cursor[a], 1);
    adj[pa] = make_int2(b, e);
    int pb = atomicAdd(&cursor[b], 1);
    adj[pb] = make_int2(a, e);
}

// ---------------------------------------------------------------------------
// Gather + finalize. 32 lanes per node. Random reads are two fp16 64B rows.
// ---------------------------------------------------------------------------
template <bool USE_SG>
__global__ __launch_bounds__(256) void gather_kernel(
    const float* __restrict__ x,  const _Float16* __restrict__ sgh,
    const float* __restrict__ ef, const float* __restrict__ h1,
    const _Float16* __restrict__ h2h,
    const int* __restrict__ deg, const int* __restrict__ cursor,
    const int2* __restrict__ adj,
    float* __restrict__ out, int N)
{
    int t = blockIdx.x * blockDim.x + threadIdx.x;
    int n = t >> 5;
    int d = t & 31;
    if (n >= N) return;

    int dg    = deg[n];
    int end   = cursor[n];      // rowptr[n+1]
    int start = end - dg;

    float s_sum = 0.0f, sh_sum = 0.0f;
    for (int k = start; k < end; ++k) {
        int2 ae = adj[k];                         // {nbr, edge}, lane-uniform
        float s;
        if (USE_SG) s = (float)sgh[(size_t)ae.y * 32 + d];
        else        s = 1.0f / (1.0f + __expf(-ef[(size_t)ae.y * 32 + d]));
        float hh = (float)h2h[(size_t)ae.x * 32 + d];
        s_sum += s;
        sh_sum = fmaf(s, hh, sh_sum);
    }

    size_t idx = (size_t)n * 32 + d;
    float h = h1[idx] + sh_sum / (EPS_DENOM + s_sum);

    float sum = h, sq = h * h;
    #pragma unroll
    for (int off = 16; off > 0; off >>= 1) {
        sum += __shfl_xor(sum, off, 32);
        sq  += __shfl_xor(sq,  off, 32);
    }
    float mu  = sum * (1.0f / 32.0f);
    float var = fmaxf(sq * (1.0f / 32.0f) - mu * mu, 0.0f);
    float hn  = (h - mu) * rsqrtf(var + EPS_NORM);

    out[idx] = x[idx] + fmaxf(hn, 0.0f);
}

// ---------------------------------------------------------------------------
extern "C" void kernel_launch(void* const* d_in, const int* in_sizes, int n_in,
                              void* d_out, int out_size, void* d_ws, size_t ws_size,
                              hipStream_t stream)
{
    const float* x   = (const float*)d_in[0];
    const float* ef  = (const float*)d_in[1];
    const float* W1a = (const float*)d_in[2];
    const float* b1a = (const float*)d_in[3];
    const float* W2a = (const float*)d_in[4];
    const float* b2a = (const float*)d_in[5];
    const float* W1b = (const float*)d_in[6];
    const float* b1b = (const float*)d_in[7];
    const float* W2b = (const float*)d_in[8];
    const float* b2b = (const float*)d_in[9];
    const int*   ei  = (const int*)d_in[10];
    float* out = (float*)d_out;

    const int N = in_sizes[0] / D;
    const int E = in_sizes[1] / D;
    const int nb = (N + 255) / 256;

    // workspace layout
    char* p = (char*)d_ws;
    float*     h1     = (float*)p;     p += (size_t)N * 32 * 4;
    _Float16*  h2h    = (_Float16*)p;  p += (size_t)N * 32 * 2;
    int*       deg    = (int*)p;       p += (size_t)N * 4;
    int*       cursor = (int*)p;       p += (size_t)N * 4;
    int*       bsum   = (int*)p;       p += 2048;
    int2*      adj    = (int2*)p;      p += (size_t)2 * E * 8;
    _Float16*  sgh    = (_Float16*)p;
    const bool use_sg = ((size_t)(p - (char*)d_ws) + (size_t)E * 64) <= ws_size;

    hipMemsetAsync(deg, 0, (size_t)N * sizeof(int), stream);

    fcnn_mfma_kernel<<<(N + 63) / 64, 256, 0, stream>>>(
        x, W1a, b1a, W2a, b2a, W1b, b1b, W2b, b2b, h1, h2h, N);

    if (use_sg) {
        int n4 = E * 8;   // E*32/4 float4 groups
        sprep_kernel<<<(n4 + 255) / 256, 256, 0, stream>>>(ef, sgh, n4);
    }

    count_kernel<<<(E + 255) / 256, 256, 0, stream>>>(ei, deg, E);
    scan1_kernel<<<nb, 256, 0, stream>>>(deg, cursor, bsum, N);
    scan2_kernel<<<1, 512, 0, stream>>>(bsum, nb);
    scan3_kernel<<<nb, 256, 0, stream>>>(cursor, bsum, N);
    fill_kernel<<<(E + 255) / 256, 256, 0, stream>>>(ei, cursor, adj, E);

    int gthreads = N * 32;
    if (use_sg)
        gather_kernel<true><<<(gthreads + 255) / 256, 256, 0, stream>>>(
            x, sgh, ef, h1, h2h, deg, cursor, adj, out, N);
    else
        gather_kernel<false><<<(gthreads + 255) / 256, 256, 0, stream>>>(
            x, sgh, ef, h1, h2h, deg, cursor, adj, out, N);
}